// Round 16
// baseline (37.753 us; speedup 1.0000x reference)
//
#include <hip/hip_runtime.h>

typedef float f32x2 __attribute__((ext_vector_type(2)));
typedef float f32x4 __attribute__((ext_vector_type(4)));
typedef short short8 __attribute__((ext_vector_type(8)));  // 8 x bf16 bits

static __device__ __forceinline__ unsigned short f2bf(float f) {
    __bf16 h = (__bf16)f;
    return __builtin_bit_cast(unsigned short, h);
}

// async global->LDS, 16B/lane: lane i fetches its own 16B (per-lane source
// address) and HW writes LDS at dest + i*16 (dest must be wave-uniform).
static __device__ __forceinline__ void gload_lds16(const void* g, void* l) {
    __builtin_amdgcn_global_load_lds(
        (const __attribute__((address_space(1))) void*)g,
        (__attribute__((address_space(3))) void*)l, 16, 0, 0);
}

// ---------------------------------------------------------------------------
// Kernel A: contract TT cores into PRE-ARRANGED bf16 weights (r15-verified).
//  WdT_sw: [q 0..3][ck 0..3][(ks2*4+kg)*64 + j][m], value Wd[k][j] with
//          k = q*256 + ck*64 + ks2*32 + kg*8 + m  -> 8KB chunks stage linearly.
//  WuT_sw: r9's XOR swizzle pre-applied per 64KB col-half.
// ---------------------------------------------------------------------------
__global__ __launch_bounds__(256) void tt_build_w_kernel(
    const float* __restrict__ d1, const float* __restrict__ d2, const float* __restrict__ d3,
    const float* __restrict__ u1, const float* __restrict__ u2, const float* __restrict__ u3,
    unsigned short* __restrict__ WdT_sw, unsigned short* __restrict__ WuT_sw)
{
    int t = blockIdx.x * 256 + threadIdx.x;
    if (t < 65536) {
        int j = t >> 10, i = t & 1023;
        int i1 = i >> 7, i2 = (i >> 3) & 15, i3 = i & 7;
        int j1 = j >> 4, j2 = (j >> 2) & 3, j3 = j & 3;
        float t3[8];
#pragma unroll
        for (int b = 0; b < 8; ++b) t3[b] = d3[(b * 8 + i3) * 4 + j3];
        float wsum = 0.f;
#pragma unroll
        for (int a = 0; a < 8; ++a) {
            float va = d1[(i1 * 4 + j1) * 8 + a];
            const float* p2 = d2 + ((a * 16 + i2) * 4 + j2) * 8;
            float wa = 0.f;
#pragma unroll
            for (int b = 0; b < 8; ++b) wa = fmaf(p2[b], t3[b], wa);
            wsum = fmaf(va, wa, wsum);
        }
        int q_ = i >> 8, ck = (i >> 6) & 3, ks2 = (i >> 5) & 1;
        int kg_ = (i >> 3) & 3, m = i & 7;
        int off = (q_ * 4 + ck) * 4096 + ((ks2 * 4 + kg_) * 64 + j) * 8 + m;
        WdT_sw[off] = f2bf(wsum);
    } else {
        int t2 = t - 65536;
        int d = t2 >> 6, k = t2 & 63;
        int k1 = k >> 4, k2 = (k >> 2) & 3, k3 = k & 3;
        int o1 = d >> 7, o2 = (d >> 3) & 15, o3 = d & 7;
        float t3[8];
#pragma unroll
        for (int b = 0; b < 8; ++b) t3[b] = u3[(b * 4 + k3) * 8 + o3];
        float wsum = 0.f;
#pragma unroll
        for (int a = 0; a < 8; ++a) {
            float va = u1[(k1 * 8 + o1) * 8 + a];
            const float* p2 = u2 + ((a * 4 + k2) * 16 + o2) * 8;
            float wa = 0.f;
#pragma unroll
            for (int b = 0; b < 8; ++b) wa = fmaf(p2[b], t3[b], wa);
            wsum = fmaf(va, wa, wsum);
        }
        int dl = d & 511, hf = d >> 9;
        int off = hf * 32768 + (dl * 8 + ((k >> 3) ^ (dl & 7))) * 8 + (k & 7);
        WuT_sw[off] = f2bf(wsum);
    }
}

// ---------------------------------------------------------------------------
// K1 v3: z = relu(x @ Wd + bd) -> zbuf[tile][m16][j64].
// 256 blocks x 512 thr (8 waves), block = 4 tiles. Wave (p,h) = tile-pair p
// (tiles 2p, 2p+1) x K-quarter h -- inner loop identical to r15's verified
// wave code. Waves p=0/1 SHARE quarter h's weights: full WdT staged once per
// block (128 KB dyn LDS; staging 64->32 MB port traffic vs r15). All chunks
// resident -> no restaging; x double-buffered with counted vmcnt(8) (never
// drains mid-loop). After compute, wlds is reused as red[2][4][2048] (+1
// barrier); reduce packs 2 bf16/dword (z-store ops halved).
// ---------------------------------------------------------------------------
__global__ __launch_bounds__(512) void tt_gemm1_kernel(
    const float* __restrict__ x, const unsigned short* __restrict__ WdT_sw,
    const float* __restrict__ bd, unsigned short* __restrict__ zbuf)
{
    extern __shared__ unsigned short wlds[];   // 128 KB: [h][ck][4096]
    const int t = threadIdx.x;
    const int lane = t & 63;
    const int w = t >> 6;          // 0..7
    const int p = w >> 2;          // tile-pair
    const int h = w & 3;           // K-quarter
    const int l15 = lane & 15;
    const int kg = lane >> 4;
    const int tile0 = blockIdx.x * 4;

    // reduce-phase constants (preloaded; q even -> colz even)
    const int uq = (t & 127) * 2;            // q = 0,2,..,254
    const int tl = t >> 7;                   // tile_local 0..3
    const int colz = (uq >> 6) * 16 + (uq & 15);
    const int rowz = ((uq & 63) >> 4) * 4;
    const f32x2 bdv = *reinterpret_cast<const f32x2*>(bd + colz);

    // ---- stage full WdT once: wave (p,h) stages chunks 2p, 2p+1 of h ------
    {
        const unsigned short* src = WdT_sw + (h * 4 + 2 * p) * 4096 + lane * 8;
        unsigned short* dst = wlds + h * 16384 + 2 * p * 4096;
#pragma unroll
        for (int i = 0; i < 16; ++i)
            gload_lds16(src + i * 512, dst + i * 512);
    }

    const float* xp0 = x + ((size_t)(tile0 + 2 * p) * 16 + l15) * 1024 + h * 256 + kg * 8;
    const float* xp1 = xp0 + 16 * 1024;
    const unsigned short* lb = wlds + h * 16384;

    f32x4 xa[8], xb[8];
#define XL8(D, o0, o1, o2, o3)                                                                     \
    asm volatile("global_load_dwordx4 %0, %1, off offset:" #o0 : "=v"(D[0]) : "v"(xp0) : "memory"); \
    asm volatile("global_load_dwordx4 %0, %1, off offset:" #o1 : "=v"(D[1]) : "v"(xp0) : "memory"); \
    asm volatile("global_load_dwordx4 %0, %1, off offset:" #o2 : "=v"(D[2]) : "v"(xp0) : "memory"); \
    asm volatile("global_load_dwordx4 %0, %1, off offset:" #o3 : "=v"(D[3]) : "v"(xp0) : "memory"); \
    asm volatile("global_load_dwordx4 %0, %1, off offset:" #o0 : "=v"(D[4]) : "v"(xp1) : "memory"); \
    asm volatile("global_load_dwordx4 %0, %1, off offset:" #o1 : "=v"(D[5]) : "v"(xp1) : "memory"); \
    asm volatile("global_load_dwordx4 %0, %1, off offset:" #o2 : "=v"(D[6]) : "v"(xp1) : "memory"); \
    asm volatile("global_load_dwordx4 %0, %1, off offset:" #o3 : "=v"(D[7]) : "v"(xp1) : "memory");

    XL8(xa, 0, 16, 128, 144)                           // ck0 x-loads
    asm volatile("s_waitcnt vmcnt(8)" ::: "memory");   // own staging done
    __syncthreads();                                   // all staging done

    f32x4 acc0[4] = {{0.f, 0.f, 0.f, 0.f}, {0.f, 0.f, 0.f, 0.f},
                     {0.f, 0.f, 0.f, 0.f}, {0.f, 0.f, 0.f, 0.f}};
    f32x4 acc1[4] = {{0.f, 0.f, 0.f, 0.f}, {0.f, 0.f, 0.f, 0.f},
                     {0.f, 0.f, 0.f, 0.f}, {0.f, 0.f, 0.f, 0.f}};

#define CPT(XS, CKOFF, WN) do {                                                             \
    asm volatile("s_waitcnt vmcnt(" #WN ")" ::: "memory");                                  \
    __builtin_amdgcn_sched_barrier(0);                                                      \
    const unsigned short* lb_ = lb + CKOFF;                                                 \
    _Pragma("unroll")                                                                       \
    for (int ks2 = 0; ks2 < 2; ++ks2) {                                                     \
        union { short8 v; unsigned short e[8]; } a0, a1;                                    \
        _Pragma("unroll")                                                                   \
        for (int e = 0; e < 4; ++e) {                                                       \
            a0.e[e] = f2bf(XS[ks2 * 2][e]);     a0.e[e + 4] = f2bf(XS[ks2 * 2 + 1][e]);     \
            a1.e[e] = f2bf(XS[4 + ks2 * 2][e]); a1.e[e + 4] = f2bf(XS[4 + ks2 * 2 + 1][e]); \
        }                                                                                   \
        _Pragma("unroll")                                                                   \
        for (int ct = 0; ct < 4; ++ct) {                                                    \
            short8 bf = *reinterpret_cast<const short8*>(                                   \
                lb_ + (ks2 * 4 + kg) * 512 + ct * 128 + l15 * 8);                           \
            acc0[ct] = __builtin_amdgcn_mfma_f32_16x16x32_bf16(a0.v, bf, acc0[ct], 0, 0, 0); \
            acc1[ct] = __builtin_amdgcn_mfma_f32_16x16x32_bf16(a1.v, bf, acc1[ct], 0, 0, 0); \
        }                                                                                   \
    }                                                                                       \
    __builtin_amdgcn_sched_barrier(0);                                                      \
} while (0)

    XL8(xb, 256, 272, 384, 400)      // ck1
    CPT(xa, 0, 8);                   // ck0 (xb in flight)
    XL8(xa, 512, 528, 640, 656)      // ck2
    CPT(xb, 4096, 8);                // ck1 (xa in flight)
    XL8(xb, 768, 784, 896, 912)      // ck3
    CPT(xa, 8192, 8);                // ck2 (xb in flight)
    CPT(xb, 12288, 0);               // ck3 (drain)
#undef XL8
#undef CPT

    __syncthreads();   // all waves done reading wlds -> safe to alias as red

    // ---- red aliased into wlds: red[p][h][tp*1024 + q*4 + r] ---------------
    float* red = reinterpret_cast<float*>(wlds);
    {
        float* rp = red + p * 8192 + h * 2048;
#pragma unroll
        for (int ct = 0; ct < 4; ++ct) {
            *reinterpret_cast<f32x4*>(rp + ct * 256 + lane * 4) = acc0[ct];
            *reinterpret_cast<f32x4*>(rp + 1024 + ct * 256 + lane * 4) = acc1[ct];
        }
    }
    __syncthreads();

    // ---- reduce + bias + relu -> zbuf (thread: tile tl, cols colz,colz+1) --
    {
        const int pp = tl >> 1, tp = tl & 1;
        const float* base = red + pp * 8192 + tp * 1024 + uq * 4;
        f32x4 s0 = {0.f, 0.f, 0.f, 0.f}, s1 = {0.f, 0.f, 0.f, 0.f};
#pragma unroll
        for (int hh = 0; hh < 4; ++hh) {
            f32x4 v0 = *reinterpret_cast<const f32x4*>(base + hh * 2048);
            f32x4 v1 = *reinterpret_cast<const f32x4*>(base + hh * 2048 + 4);
#pragma unroll
            for (int r = 0; r < 4; ++r) { s0[r] += v0[r]; s1[r] += v1[r]; }
        }
        const int tile = tile0 + tl;
#pragma unroll
        for (int r = 0; r < 4; ++r) {
            float z0 = s0[r] + bdv[0]; z0 = z0 > 0.f ? z0 : 0.f;
            float z1 = s1[r] + bdv[1]; z1 = z1 > 0.f ? z1 : 0.f;
            unsigned int pk = (unsigned int)f2bf(z0) | ((unsigned int)f2bf(z1) << 16);
            *reinterpret_cast<unsigned int*>(zbuf + tile * 1024 + (rowz + r) * 64 + colz) = pk;
        }
    }
}

// ---------------------------------------------------------------------------
// K2: y = z @ Wu + bu (byte-identical to r15, verified). 256 blocks x 4 waves,
// block = 8 tiles x col-half; WuT-half staged via gload_lds from pre-swizzled
// layout; swapped MFMA -> dwordx4 stores.
// ---------------------------------------------------------------------------
__global__ __launch_bounds__(256) void tt_gemm2_kernel(
    const unsigned short* __restrict__ zbuf, const unsigned short* __restrict__ WuT_sw,
    const float* __restrict__ bu, float* __restrict__ y)
{
    __shared__ unsigned short wlds2[32768];   // 64 KB
    const int t = threadIdx.x;
    const int lane = t & 63;
    const int w = t >> 6;
    const int l15 = lane & 15;
    const int kg = lane >> 4;
    const int ch = blockIdx.x & 1;
    const int rg = blockIdx.x >> 1;          // 0..127

    const unsigned short* src = WuT_sw + ch * 32768 + w * 8192 + lane * 8;
#pragma unroll
    for (int i = 0; i < 16; ++i)
        gload_lds16(src + i * 512, &wlds2[w * 8192 + i * 512]);

    f32x4 bv[8];
#pragma unroll
    for (int i = 0; i < 8; ++i)
        bv[i] = *reinterpret_cast<const f32x4*>(bu + ch * 512 + w * 128 + i * 16 + kg * 4);
    __syncthreads();

#pragma unroll
    for (int tt = 0; tt < 8; ++tt) {
        const int tile = rg * 8 + tt;
        short8 az0 = *reinterpret_cast<const short8*>(zbuf + tile * 1024 + l15 * 64 + kg * 8);
        short8 az1 = *reinterpret_cast<const short8*>(zbuf + tile * 1024 + l15 * 64 + 32 + kg * 8);
        const size_t yb = (size_t)(tile * 16 + l15) * 1024 + ch * 512 + w * 128;
#pragma unroll
        for (int i = 0; i < 8; ++i) {
            const int row = w * 128 + i * 16 + l15;
            const int s = row & 7;
            short8 b0 = *reinterpret_cast<const short8*>(&wlds2[(row * 8 + (kg ^ s)) * 8]);
            short8 b1 = *reinterpret_cast<const short8*>(&wlds2[(row * 8 + ((kg + 4) ^ s)) * 8]);
            f32x4 c = {0.f, 0.f, 0.f, 0.f};
            c = __builtin_amdgcn_mfma_f32_16x16x32_bf16(b0, az0, c, 0, 0, 0);
            c = __builtin_amdgcn_mfma_f32_16x16x32_bf16(b1, az1, c, 0, 0, 0);
            f32x4 o;
#pragma unroll
            for (int r = 0; r < 4; ++r) o[r] = c[r] + bv[i][r];
            *reinterpret_cast<f32x4*>(y + yb + i * 16 + kg * 4) = o;
        }
    }
}

extern "C" void kernel_launch(void* const* d_in, const int* in_sizes, int n_in,
                              void* d_out, int out_size, void* d_ws, size_t ws_size,
                              hipStream_t stream) {
    const float* x  = (const float*)d_in[0];
    const float* d1 = (const float*)d_in[1];
    const float* d2 = (const float*)d_in[2];
    const float* d3 = (const float*)d_in[3];
    const float* u1 = (const float*)d_in[4];
    const float* u2 = (const float*)d_in[5];
    const float* u3 = (const float*)d_in[6];
    const float* bd = (const float*)d_in[7];
    const float* bu = (const float*)d_in[8];
    float* y = (float*)d_out;
    unsigned short* WdT_sw = (unsigned short*)d_ws;   // 128 KB, staged layout
    unsigned short* WuT_sw = WdT_sw + 65536;          // 128 KB, pre-swizzled
    unsigned short* zbuf   = WuT_sw + 65536;          // 2 MB

    hipLaunchKernelGGL(tt_build_w_kernel, dim3(512), dim3(256), 0, stream,
                       d1, d2, d3, u1, u2, u3, WdT_sw, WuT_sw);
    hipLaunchKernelGGL(tt_gemm1_kernel, dim3(256), dim3(512), 131072, stream,
                       x, WdT_sw, bd, zbuf);
    hipLaunchKernelGGL(tt_gemm2_kernel, dim3(256), dim3(256), 0, stream,
                       zbuf, WuT_sw, bu, y);
}

// Round 17
// 35.762 us; speedup vs baseline: 1.0557x; 1.0557x over previous
//
#include <hip/hip_runtime.h>

typedef float f32x2 __attribute__((ext_vector_type(2)));
typedef float f32x4 __attribute__((ext_vector_type(4)));
typedef short short8 __attribute__((ext_vector_type(8)));  // 8 x bf16 bits

static __device__ __forceinline__ unsigned short f2bf(float f) {
    __bf16 h = (__bf16)f;
    return __builtin_bit_cast(unsigned short, h);
}

// async global->LDS, 16B/lane (gemm2 staging only)
static __device__ __forceinline__ void gload_lds16(const void* g, void* l) {
    __builtin_amdgcn_global_load_lds(
        (const __attribute__((address_space(1))) void*)g,
        (__attribute__((address_space(3))) void*)l, 16, 0, 0);
}

// ---------------------------------------------------------------------------
// Kernel A (byte-identical to r15): PRE-ARRANGED bf16 weights.
//  WdT_sw: [q][ck][(ks2*4+kg)*64 + j][m], value Wd[k][j],
//          k = q*256 + ck*64 + ks2*32 + kg*8 + m.
//  WuT_sw: r9's XOR swizzle pre-applied per 64KB col-half.
// ---------------------------------------------------------------------------
__global__ __launch_bounds__(256) void tt_build_w_kernel(
    const float* __restrict__ d1, const float* __restrict__ d2, const float* __restrict__ d3,
    const float* __restrict__ u1, const float* __restrict__ u2, const float* __restrict__ u3,
    unsigned short* __restrict__ WdT_sw, unsigned short* __restrict__ WuT_sw)
{
    int t = blockIdx.x * 256 + threadIdx.x;
    if (t < 65536) {
        int j = t >> 10, i = t & 1023;
        int i1 = i >> 7, i2 = (i >> 3) & 15, i3 = i & 7;
        int j1 = j >> 4, j2 = (j >> 2) & 3, j3 = j & 3;
        float t3[8];
#pragma unroll
        for (int b = 0; b < 8; ++b) t3[b] = d3[(b * 8 + i3) * 4 + j3];
        float wsum = 0.f;
#pragma unroll
        for (int a = 0; a < 8; ++a) {
            float va = d1[(i1 * 4 + j1) * 8 + a];
            const float* p2 = d2 + ((a * 16 + i2) * 4 + j2) * 8;
            float wa = 0.f;
#pragma unroll
            for (int b = 0; b < 8; ++b) wa = fmaf(p2[b], t3[b], wa);
            wsum = fmaf(va, wa, wsum);
        }
        int q_ = i >> 8, ck = (i >> 6) & 3, ks2 = (i >> 5) & 1;
        int kg_ = (i >> 3) & 3, m = i & 7;
        int off = (q_ * 4 + ck) * 4096 + ((ks2 * 4 + kg_) * 64 + j) * 8 + m;
        WdT_sw[off] = f2bf(wsum);
    } else {
        int t2 = t - 65536;
        int d = t2 >> 6, k = t2 & 63;
        int k1 = k >> 4, k2 = (k >> 2) & 3, k3 = k & 3;
        int o1 = d >> 7, o2 = (d >> 3) & 15, o3 = d & 7;
        float t3[8];
#pragma unroll
        for (int b = 0; b < 8; ++b) t3[b] = u3[(b * 4 + k3) * 8 + o3];
        float wsum = 0.f;
#pragma unroll
        for (int a = 0; a < 8; ++a) {
            float va = u1[(k1 * 8 + o1) * 8 + a];
            const float* p2 = u2 + ((a * 4 + k2) * 16 + o2) * 8;
            float wa = 0.f;
#pragma unroll
            for (int b = 0; b < 8; ++b) wa = fmaf(p2[b], t3[b], wa);
            wsum = fmaf(va, wa, wsum);
        }
        int dl = d & 511, hf = d >> 9;
        int off = hf * 32768 + (dl * 8 + ((k >> 3) ^ (dl & 7))) * 8 + (k & 7);
        WuT_sw[off] = f2bf(wsum);
    }
}

// ---------------------------------------------------------------------------
// K1 v4: z = relu(x @ Wd + bd). 256 blocks x 256 thr (4 waves), block = 4
// tiles. Wave h = K-quarter. Weights DIRECT L2->VGPR (no LDS hop, no
// residency): each weight frag is loaded once and feeds 4 MFMAs (4 tiles) ->
// weight port traffic 64->32 MB vs r15, LDS = 64 KB reduce buffer only.
// Pipeline: per k-step (K=32) issue {8 x-loads + 4 W-loads} pinned asm,
// dbuf 2-deep, counted vmcnt(12) (never drains mid-loop). Frag math and
// reduce formulas byte-carried from r15/r9 (verified): WdT_sw frag addr
// = base + ks*4096B + ct*256B, base = h*16384 + kg*512 + l15*8 (elems).
// ---------------------------------------------------------------------------
__global__ __launch_bounds__(256) void tt_gemm1_kernel(
    const float* __restrict__ x, const unsigned short* __restrict__ WdT_sw,
    const float* __restrict__ bd, unsigned short* __restrict__ zbuf)
{
    __shared__ float red[4][4][1024];   // [tile][h][elem] = 64 KB
    const int t = threadIdx.x;
    const int lane = t & 63;
    const int h = t >> 6;          // K-quarter 0..3
    const int l15 = lane & 15;
    const int kg = lane >> 4;
    const int tile0 = blockIdx.x * 4;

    // reduce-phase constants (r9-verified mapping); bd load is pre-asm
    // (position in FIFO is irrelevant: each vmcnt(12) keeps only the newest
    // 12 = just-issued step, everything older is guaranteed drained)
    const int colz = (t >> 6) * 16 + (t & 15);
    const int rowz = ((t & 63) >> 4) * 4;
    const float bdv = bd[colz];

    const float* xp0 = x + ((size_t)(tile0 + 0) * 16 + l15) * 1024 + h * 256 + kg * 8;
    const float* xp1 = xp0 + 16 * 1024;
    const float* xp2 = xp0 + 32 * 1024;
    const float* xp3 = xp0 + 48 * 1024;
    const unsigned short* wqb = WdT_sw + h * 16384 + kg * 512 + l15 * 8;
    const unsigned short* wq0 = wqb;
    const unsigned short* wq1 = wqb + 2048;
    const unsigned short* wq2 = wqb + 4096;
    const unsigned short* wq3 = wqb + 6144;
    const unsigned short* wq4 = wqb + 8192;
    const unsigned short* wq5 = wqb + 10240;
    const unsigned short* wq6 = wqb + 12288;
    const unsigned short* wq7 = wqb + 14336;

    f32x4 xA[8], xB[8];
    short8 wA[4], wB[4];
    f32x4 acc[4][4];
#pragma unroll
    for (int t4 = 0; t4 < 4; ++t4)
#pragma unroll
        for (int ct = 0; ct < 4; ++ct) acc[t4][ct] = {0.f, 0.f, 0.f, 0.f};

// issue k-step: 8 x-loads (4 tiles x 2) + 4 W-loads (ct 0..3), 12 total
#define ISSUE(D, W, WQ, O0, O1)                                                                   \
    asm volatile("global_load_dwordx4 %0, %1, off offset:" #O0 : "=v"(D[0]) : "v"(xp0) : "memory"); \
    asm volatile("global_load_dwordx4 %0, %1, off offset:" #O1 : "=v"(D[1]) : "v"(xp0) : "memory"); \
    asm volatile("global_load_dwordx4 %0, %1, off offset:" #O0 : "=v"(D[2]) : "v"(xp1) : "memory"); \
    asm volatile("global_load_dwordx4 %0, %1, off offset:" #O1 : "=v"(D[3]) : "v"(xp1) : "memory"); \
    asm volatile("global_load_dwordx4 %0, %1, off offset:" #O0 : "=v"(D[4]) : "v"(xp2) : "memory"); \
    asm volatile("global_load_dwordx4 %0, %1, off offset:" #O1 : "=v"(D[5]) : "v"(xp2) : "memory"); \
    asm volatile("global_load_dwordx4 %0, %1, off offset:" #O0 : "=v"(D[6]) : "v"(xp3) : "memory"); \
    asm volatile("global_load_dwordx4 %0, %1, off offset:" #O1 : "=v"(D[7]) : "v"(xp3) : "memory"); \
    asm volatile("global_load_dwordx4 %0, %1, off offset:0"   : "=v"(W[0]) : "v"(WQ) : "memory");   \
    asm volatile("global_load_dwordx4 %0, %1, off offset:256" : "=v"(W[1]) : "v"(WQ) : "memory");   \
    asm volatile("global_load_dwordx4 %0, %1, off offset:512" : "=v"(W[2]) : "v"(WQ) : "memory");   \
    asm volatile("global_load_dwordx4 %0, %1, off offset:768" : "=v"(W[3]) : "v"(WQ) : "memory");

// compute k-step from (D,W): 4 A-frags, 16 MFMA
#define CPT(D, W, WN) do {                                                                   \
    asm volatile("s_waitcnt vmcnt(" #WN ")" ::: "memory");                                   \
    __builtin_amdgcn_sched_barrier(0);                                                       \
    _Pragma("unroll")                                                                        \
    for (int t4 = 0; t4 < 4; ++t4) {                                                         \
        union { short8 v; unsigned short e[8]; } a;                                          \
        _Pragma("unroll")                                                                    \
        for (int e = 0; e < 4; ++e) {                                                        \
            a.e[e]     = f2bf(D[2 * t4][e]);                                                 \
            a.e[e + 4] = f2bf(D[2 * t4 + 1][e]);                                             \
        }                                                                                    \
        _Pragma("unroll")                                                                    \
        for (int ct = 0; ct < 4; ++ct)                                                       \
            acc[t4][ct] = __builtin_amdgcn_mfma_f32_16x16x32_bf16(a.v, W[ct], acc[t4][ct],   \
                                                                  0, 0, 0);                  \
    }                                                                                        \
    __builtin_amdgcn_sched_barrier(0);                                                       \
} while (0)

    ISSUE(xA, wA, wq0, 0, 16)        // ks0
    ISSUE(xB, wB, wq1, 128, 144)     // ks1
    CPT(xA, wA, 12); ISSUE(xA, wA, wq2, 256, 272)   // ks0 | ks2
    CPT(xB, wB, 12); ISSUE(xB, wB, wq3, 384, 400)   // ks1 | ks3
    CPT(xA, wA, 12); ISSUE(xA, wA, wq4, 512, 528)   // ks2 | ks4
    CPT(xB, wB, 12); ISSUE(xB, wB, wq5, 640, 656)   // ks3 | ks5
    CPT(xA, wA, 12); ISSUE(xA, wA, wq6, 768, 784)   // ks4 | ks6
    CPT(xB, wB, 12); ISSUE(xB, wB, wq7, 896, 912)   // ks5 | ks7
    CPT(xA, wA, 12);                                // ks6
    CPT(xB, wB, 0);                                 // ks7 (drain)
#undef ISSUE
#undef CPT

    // ---- reduce: acc -> red -> bias/relu -> zbuf (r9-verified formulas) ----
#pragma unroll
    for (int t4 = 0; t4 < 4; ++t4)
#pragma unroll
        for (int ct = 0; ct < 4; ++ct)
            *reinterpret_cast<f32x4*>(&red[t4][h][ct * 256 + lane * 4]) = acc[t4][ct];
    __syncthreads();
#pragma unroll
    for (int t4 = 0; t4 < 4; ++t4) {
        f32x4 v0 = *reinterpret_cast<const f32x4*>(&red[t4][0][t * 4]);
        f32x4 v1 = *reinterpret_cast<const f32x4*>(&red[t4][1][t * 4]);
        f32x4 v2 = *reinterpret_cast<const f32x4*>(&red[t4][2][t * 4]);
        f32x4 v3 = *reinterpret_cast<const f32x4*>(&red[t4][3][t * 4]);
        const int tile = tile0 + t4;
#pragma unroll
        for (int r = 0; r < 4; ++r) {
            float zz = v0[r] + v1[r] + v2[r] + v3[r] + bdv;
            zz = zz > 0.f ? zz : 0.f;
            zbuf[tile * 1024 + (rowz + r) * 64 + colz] = f2bf(zz);
        }
    }
}

// ---------------------------------------------------------------------------
// K2: y = z @ Wu + bu (byte-identical to r15, verified). 256 blocks x 4
// waves, block = 8 tiles x col-half; WuT-half staged via gload_lds from the
// pre-swizzled layout; swapped MFMA -> dwordx4 stores.
// ---------------------------------------------------------------------------
__global__ __launch_bounds__(256) void tt_gemm2_kernel(
    const unsigned short* __restrict__ zbuf, const unsigned short* __restrict__ WuT_sw,
    const float* __restrict__ bu, float* __restrict__ y)
{
    __shared__ unsigned short wlds2[32768];   // 64 KB
    const int t = threadIdx.x;
    const int lane = t & 63;
    const int w = t >> 6;
    const int l15 = lane & 15;
    const int kg = lane >> 4;
    const int ch = blockIdx.x & 1;
    const int rg = blockIdx.x >> 1;          // 0..127

    const unsigned short* src = WuT_sw + ch * 32768 + w * 8192 + lane * 8;
#pragma unroll
    for (int i = 0; i < 16; ++i)
        gload_lds16(src + i * 512, &wlds2[w * 8192 + i * 512]);

    f32x4 bv[8];
#pragma unroll
    for (int i = 0; i < 8; ++i)
        bv[i] = *reinterpret_cast<const f32x4*>(bu + ch * 512 + w * 128 + i * 16 + kg * 4);
    __syncthreads();

#pragma unroll
    for (int tt = 0; tt < 8; ++tt) {
        const int tile = rg * 8 + tt;
        short8 az0 = *reinterpret_cast<const short8*>(zbuf + tile * 1024 + l15 * 64 + kg * 8);
        short8 az1 = *reinterpret_cast<const short8*>(zbuf + tile * 1024 + l15 * 64 + 32 + kg * 8);
        const size_t yb = (size_t)(tile * 16 + l15) * 1024 + ch * 512 + w * 128;
#pragma unroll
        for (int i = 0; i < 8; ++i) {
            const int row = w * 128 + i * 16 + l15;
            const int s = row & 7;
            short8 b0 = *reinterpret_cast<const short8*>(&wlds2[(row * 8 + (kg ^ s)) * 8]);
            short8 b1 = *reinterpret_cast<const short8*>(&wlds2[(row * 8 + ((kg + 4) ^ s)) * 8]);
            f32x4 c = {0.f, 0.f, 0.f, 0.f};
            c = __builtin_amdgcn_mfma_f32_16x16x32_bf16(b0, az0, c, 0, 0, 0);
            c = __builtin_amdgcn_mfma_f32_16x16x32_bf16(b1, az1, c, 0, 0, 0);
            f32x4 o;
#pragma unroll
            for (int r = 0; r < 4; ++r) o[r] = c[r] + bv[i][r];
            *reinterpret_cast<f32x4*>(y + yb + i * 16 + kg * 4) = o;
        }
    }
}

extern "C" void kernel_launch(void* const* d_in, const int* in_sizes, int n_in,
                              void* d_out, int out_size, void* d_ws, size_t ws_size,
                              hipStream_t stream) {
    const float* x  = (const float*)d_in[0];
    const float* d1 = (const float*)d_in[1];
    const float* d2 = (const float*)d_in[2];
    const float* d3 = (const float*)d_in[3];
    const float* u1 = (const float*)d_in[4];
    const float* u2 = (const float*)d_in[5];
    const float* u3 = (const float*)d_in[6];
    const float* bd = (const float*)d_in[7];
    const float* bu = (const float*)d_in[8];
    float* y = (float*)d_out;
    unsigned short* WdT_sw = (unsigned short*)d_ws;   // 128 KB, staged layout
    unsigned short* WuT_sw = WdT_sw + 65536;          // 128 KB, pre-swizzled
    unsigned short* zbuf   = WuT_sw + 65536;          // 2 MB

    hipLaunchKernelGGL(tt_build_w_kernel, dim3(512), dim3(256), 0, stream,
                       d1, d2, d3, u1, u2, u3, WdT_sw, WuT_sw);
    hipLaunchKernelGGL(tt_gemm1_kernel, dim3(256), dim3(256), 0, stream,
                       x, WdT_sw, bd, zbuf);
    hipLaunchKernelGGL(tt_gemm2_kernel, dim3(256), dim3(256), 0, stream,
                       zbuf, WuT_sw, bu, y);
}

// Round 18
// 33.661 us; speedup vs baseline: 1.1216x; 1.0624x over previous
//
#include <hip/hip_runtime.h>

typedef float f32x2 __attribute__((ext_vector_type(2)));
typedef float f32x4 __attribute__((ext_vector_type(4)));
typedef short short8 __attribute__((ext_vector_type(8)));  // 8 x bf16 bits

static __device__ __forceinline__ unsigned short f2bf(float f) {
    __bf16 h = (__bf16)f;
    return __builtin_bit_cast(unsigned short, h);
}

// async global->LDS, 16B/lane (WuT staging)
static __device__ __forceinline__ void gload_lds16(const void* g, void* l) {
    __builtin_amdgcn_global_load_lds(
        (const __attribute__((address_space(1))) void*)g,
        (__attribute__((address_space(3))) void*)l, 16, 0, 0);
}

// ---------------------------------------------------------------------------
// Kernel A (byte-identical to r15/r17): PRE-ARRANGED bf16 weights.
//  WdT_sw: [q][ck][(ks2*4+kg)*64 + j][m], value Wd[k][j],
//          k = q*256 + ck*64 + ks2*32 + kg*8 + m.
//  WuT_sw: r9's XOR swizzle pre-applied per 64KB col-half.
// ---------------------------------------------------------------------------
__global__ __launch_bounds__(256) void tt_build_w_kernel(
    const float* __restrict__ d1, const float* __restrict__ d2, const float* __restrict__ d3,
    const float* __restrict__ u1, const float* __restrict__ u2, const float* __restrict__ u3,
    unsigned short* __restrict__ WdT_sw, unsigned short* __restrict__ WuT_sw)
{
    int t = blockIdx.x * 256 + threadIdx.x;
    if (t < 65536) {
        int j = t >> 10, i = t & 1023;
        int i1 = i >> 7, i2 = (i >> 3) & 15, i3 = i & 7;
        int j1 = j >> 4, j2 = (j >> 2) & 3, j3 = j & 3;
        float t3[8];
#pragma unroll
        for (int b = 0; b < 8; ++b) t3[b] = d3[(b * 8 + i3) * 4 + j3];
        float wsum = 0.f;
#pragma unroll
        for (int a = 0; a < 8; ++a) {
            float va = d1[(i1 * 4 + j1) * 8 + a];
            const float* p2 = d2 + ((a * 16 + i2) * 4 + j2) * 8;
            float wa = 0.f;
#pragma unroll
            for (int b = 0; b < 8; ++b) wa = fmaf(p2[b], t3[b], wa);
            wsum = fmaf(va, wa, wsum);
        }
        int q_ = i >> 8, ck = (i >> 6) & 3, ks2 = (i >> 5) & 1;
        int kg_ = (i >> 3) & 3, m = i & 7;
        int off = (q_ * 4 + ck) * 4096 + ((ks2 * 4 + kg_) * 64 + j) * 8 + m;
        WdT_sw[off] = f2bf(wsum);
    } else {
        int t2 = t - 65536;
        int d = t2 >> 6, k = t2 & 63;
        int k1 = k >> 4, k2 = (k >> 2) & 3, k3 = k & 3;
        int o1 = d >> 7, o2 = (d >> 3) & 15, o3 = d & 7;
        float t3[8];
#pragma unroll
        for (int b = 0; b < 8; ++b) t3[b] = u3[(b * 4 + k3) * 8 + o3];
        float wsum = 0.f;
#pragma unroll
        for (int a = 0; a < 8; ++a) {
            float va = u1[(k1 * 8 + o1) * 8 + a];
            const float* p2 = u2 + ((a * 4 + k2) * 16 + o2) * 8;
            float wa = 0.f;
#pragma unroll
            for (int b = 0; b < 8; ++b) wa = fmaf(p2[b], t3[b], wa);
            wsum = fmaf(va, wa, wsum);
        }
        int dl = d & 511, hf = d >> 9;
        int off = hf * 32768 + (dl * 8 + ((k >> 3) ^ (dl & 7))) * 8 + (k & 7);
        WuT_sw[off] = f2bf(wsum);
    }
}

// ---------------------------------------------------------------------------
// FUSED kernel: y = relu(x@Wd+bd)@Wu + bu. 256 blocks x 256 thr (4 waves),
// block = 4 row-tiles.
// Phase A (byte-carry of r17 gemm1, verified): wave h = K-quarter; weights
//   direct L2->VGPR, each W-frag feeds 4 MFMAs (4 tiles); per k-step issue
//   {8 x + 4 W} pinned asm, dbuf 2-deep, counted vmcnt(12), drain only at
//   tail. Reduce via red LDS -> bias+relu -> z to LDS (r4's stride-80
//   layout, verified) -- NO z global roundtrip.
// Phase B (r15 gemm2 loop, verified): 2 passes over col-halves; WuT-half
//   (64 KB, pre-swizzled) staged into the REUSED red buffer via gload_lds;
//   z frags from zlds; swapped MFMA -> dwordx4 y stores.
// Port traffic: x 64 + Wd 32 + WuT 32 + y 64 = 192 MB; one launch gap killed.
// LDS: 64 KB red/WuT + 10 KB zlds = 74 KB -> 2 blocks/CU capacity.
// ---------------------------------------------------------------------------
__global__ __launch_bounds__(256) void tt_fused_kernel(
    const float* __restrict__ x, const unsigned short* __restrict__ WdT_sw,
    const unsigned short* __restrict__ WuT_sw, const float* __restrict__ bd,
    const float* __restrict__ bu, float* __restrict__ y)
{
    __shared__ float red[4][4][1024];            // 64 KB; reused as WuT stage
    __shared__ unsigned short zlds[4][16 * 80];  // 10 KB, r4-verified layout
    const int t = threadIdx.x;
    const int lane = t & 63;
    const int h = t >> 6;          // wave id: K-quarter (A) / col-128 (B)
    const int l15 = lane & 15;
    const int kg = lane >> 4;
    const int tile0 = blockIdx.x * 4;

    // reduce-phase constants (r9-verified mapping)
    const int colz = (t >> 6) * 16 + (t & 15);
    const int rowz = ((t & 63) >> 4) * 4;
    const float bdv = bd[colz];

    const float* xp0 = x + ((size_t)(tile0 + 0) * 16 + l15) * 1024 + h * 256 + kg * 8;
    const float* xp1 = xp0 + 16 * 1024;
    const float* xp2 = xp0 + 32 * 1024;
    const float* xp3 = xp0 + 48 * 1024;
    const unsigned short* wqb = WdT_sw + h * 16384 + kg * 512 + l15 * 8;
    const unsigned short* wq0 = wqb;
    const unsigned short* wq1 = wqb + 2048;
    const unsigned short* wq2 = wqb + 4096;
    const unsigned short* wq3 = wqb + 6144;
    const unsigned short* wq4 = wqb + 8192;
    const unsigned short* wq5 = wqb + 10240;
    const unsigned short* wq6 = wqb + 12288;
    const unsigned short* wq7 = wqb + 14336;

    f32x4 xA[8], xB[8];
    short8 wA[4], wB[4];
    f32x4 acc[4][4];
#pragma unroll
    for (int t4 = 0; t4 < 4; ++t4)
#pragma unroll
        for (int ct = 0; ct < 4; ++ct) acc[t4][ct] = {0.f, 0.f, 0.f, 0.f};

#define ISSUE(D, W, WQ, O0, O1)                                                                   \
    asm volatile("global_load_dwordx4 %0, %1, off offset:" #O0 : "=v"(D[0]) : "v"(xp0) : "memory"); \
    asm volatile("global_load_dwordx4 %0, %1, off offset:" #O1 : "=v"(D[1]) : "v"(xp0) : "memory"); \
    asm volatile("global_load_dwordx4 %0, %1, off offset:" #O0 : "=v"(D[2]) : "v"(xp1) : "memory"); \
    asm volatile("global_load_dwordx4 %0, %1, off offset:" #O1 : "=v"(D[3]) : "v"(xp1) : "memory"); \
    asm volatile("global_load_dwordx4 %0, %1, off offset:" #O0 : "=v"(D[4]) : "v"(xp2) : "memory"); \
    asm volatile("global_load_dwordx4 %0, %1, off offset:" #O1 : "=v"(D[5]) : "v"(xp2) : "memory"); \
    asm volatile("global_load_dwordx4 %0, %1, off offset:" #O0 : "=v"(D[6]) : "v"(xp3) : "memory"); \
    asm volatile("global_load_dwordx4 %0, %1, off offset:" #O1 : "=v"(D[7]) : "v"(xp3) : "memory"); \
    asm volatile("global_load_dwordx4 %0, %1, off offset:0"   : "=v"(W[0]) : "v"(WQ) : "memory");   \
    asm volatile("global_load_dwordx4 %0, %1, off offset:256" : "=v"(W[1]) : "v"(WQ) : "memory");   \
    asm volatile("global_load_dwordx4 %0, %1, off offset:512" : "=v"(W[2]) : "v"(WQ) : "memory");   \
    asm volatile("global_load_dwordx4 %0, %1, off offset:768" : "=v"(W[3]) : "v"(WQ) : "memory");

#define CPT(D, W, WN) do {                                                                   \
    asm volatile("s_waitcnt vmcnt(" #WN ")" ::: "memory");                                   \
    __builtin_amdgcn_sched_barrier(0);                                                       \
    _Pragma("unroll")                                                                        \
    for (int t4 = 0; t4 < 4; ++t4) {                                                         \
        union { short8 v; unsigned short e[8]; } a;                                          \
        _Pragma("unroll")                                                                    \
        for (int e = 0; e < 4; ++e) {                                                        \
            a.e[e]     = f2bf(D[2 * t4][e]);                                                 \
            a.e[e + 4] = f2bf(D[2 * t4 + 1][e]);                                             \
        }                                                                                    \
        _Pragma("unroll")                                                                    \
        for (int ct = 0; ct < 4; ++ct)                                                       \
            acc[t4][ct] = __builtin_amdgcn_mfma_f32_16x16x32_bf16(a.v, W[ct], acc[t4][ct],   \
                                                                  0, 0, 0);                  \
    }                                                                                        \
    __builtin_amdgcn_sched_barrier(0);                                                       \
} while (0)

    ISSUE(xA, wA, wq0, 0, 16)
    ISSUE(xB, wB, wq1, 128, 144)
    CPT(xA, wA, 12); ISSUE(xA, wA, wq2, 256, 272)
    CPT(xB, wB, 12); ISSUE(xB, wB, wq3, 384, 400)
    CPT(xA, wA, 12); ISSUE(xA, wA, wq4, 512, 528)
    CPT(xB, wB, 12); ISSUE(xB, wB, wq5, 640, 656)
    CPT(xA, wA, 12); ISSUE(xA, wA, wq6, 768, 784)
    CPT(xB, wB, 12); ISSUE(xB, wB, wq7, 896, 912)
    CPT(xA, wA, 12);
    CPT(xB, wB, 0);
#undef ISSUE
#undef CPT

    // ---- reduce: acc -> red -> bias/relu -> zlds (r4-verified layout) -----
#pragma unroll
    for (int t4 = 0; t4 < 4; ++t4)
#pragma unroll
        for (int ct = 0; ct < 4; ++ct)
            *reinterpret_cast<f32x4*>(&red[t4][h][ct * 256 + lane * 4]) = acc[t4][ct];
    __syncthreads();
#pragma unroll
    for (int t4 = 0; t4 < 4; ++t4) {
        f32x4 v0 = *reinterpret_cast<const f32x4*>(&red[t4][0][t * 4]);
        f32x4 v1 = *reinterpret_cast<const f32x4*>(&red[t4][1][t * 4]);
        f32x4 v2 = *reinterpret_cast<const f32x4*>(&red[t4][2][t * 4]);
        f32x4 v3 = *reinterpret_cast<const f32x4*>(&red[t4][3][t * 4]);
#pragma unroll
        for (int r = 0; r < 4; ++r) {
            float zz = v0[r] + v1[r] + v2[r] + v3[r] + bdv;
            zz = zz > 0.f ? zz : 0.f;
            zlds[t4][(rowz + r) * 80 + colz] = f2bf(zz);
        }
    }
    __syncthreads();   // red free; zlds visible

    // ---- phase B: 2 col-half passes; WuT staged into reused red space -----
    unsigned short* wlds = reinterpret_cast<unsigned short*>(&red[0][0][0]);
    const int w = h;   // wave covers cols ch*512 + w*128 + [0,128)
#pragma unroll
    for (int ch = 0; ch < 2; ++ch) {
        const unsigned short* src = WuT_sw + ch * 32768 + w * 8192 + lane * 8;
#pragma unroll
        for (int i = 0; i < 16; ++i)
            gload_lds16(src + i * 512, wlds + w * 8192 + i * 512);
        f32x4 bv[8];
#pragma unroll
        for (int i = 0; i < 8; ++i)
            bv[i] = *reinterpret_cast<const f32x4*>(bu + ch * 512 + w * 128 + i * 16 + kg * 4);
        __syncthreads();   // staging visible (barrier drains vmcnt)

#pragma unroll
        for (int tt = 0; tt < 4; ++tt) {
            const int tile = tile0 + tt;
            short8 az0 = *reinterpret_cast<const short8*>(&zlds[tt][l15 * 80 + kg * 8]);
            short8 az1 = *reinterpret_cast<const short8*>(&zlds[tt][l15 * 80 + 32 + kg * 8]);
            const size_t yb = (size_t)(tile * 16 + l15) * 1024 + ch * 512 + w * 128;
#pragma unroll
            for (int i = 0; i < 8; ++i) {
                const int row = w * 128 + i * 16 + l15;
                const int s = row & 7;
                short8 b0 = *reinterpret_cast<const short8*>(&wlds[(row * 8 + (kg ^ s)) * 8]);
                short8 b1 = *reinterpret_cast<const short8*>(&wlds[(row * 8 + ((kg + 4) ^ s)) * 8]);
                f32x4 c = {0.f, 0.f, 0.f, 0.f};
                c = __builtin_amdgcn_mfma_f32_16x16x32_bf16(b0, az0, c, 0, 0, 0);
                c = __builtin_amdgcn_mfma_f32_16x16x32_bf16(b1, az1, c, 0, 0, 0);
                f32x4 o;
#pragma unroll
                for (int r = 0; r < 4; ++r) o[r] = c[r] + bv[i][r];
                *reinterpret_cast<f32x4*>(y + yb + i * 16 + kg * 4) = o;
            }
        }
        __syncthreads();   // wlds reads done before next pass restages
    }
}

extern "C" void kernel_launch(void* const* d_in, const int* in_sizes, int n_in,
                              void* d_out, int out_size, void* d_ws, size_t ws_size,
                              hipStream_t stream) {
    const float* x  = (const float*)d_in[0];
    const float* d1 = (const float*)d_in[1];
    const float* d2 = (const float*)d_in[2];
    const float* d3 = (const float*)d_in[3];
    const float* u1 = (const float*)d_in[4];
    const float* u2 = (const float*)d_in[5];
    const float* u3 = (const float*)d_in[6];
    const float* bd = (const float*)d_in[7];
    const float* bu = (const float*)d_in[8];
    float* y = (float*)d_out;
    unsigned short* WdT_sw = (unsigned short*)d_ws;   // 128 KB, staged layout
    unsigned short* WuT_sw = WdT_sw + 65536;          // 128 KB, pre-swizzled

    hipLaunchKernelGGL(tt_build_w_kernel, dim3(512), dim3(256), 0, stream,
                       d1, d2, d3, u1, u2, u3, WdT_sw, WuT_sw);
    hipLaunchKernelGGL(tt_fused_kernel, dim3(256), dim3(256), 0, stream,
                       x, WdT_sw, WuT_sw, bd, bu, y);
}

// Round 20
// 33.314 us; speedup vs baseline: 1.1333x; 1.0104x over previous
//
#include <hip/hip_runtime.h>

typedef float f32x2 __attribute__((ext_vector_type(2)));
typedef float f32x4 __attribute__((ext_vector_type(4)));
typedef short short8 __attribute__((ext_vector_type(8)));  // 8 x bf16 bits

static __device__ __forceinline__ unsigned short f2bf(float f) {
    __bf16 h = (__bf16)f;
    return __builtin_bit_cast(unsigned short, h);
}

// async global->LDS, 16B/lane (WuT staging)
static __device__ __forceinline__ void gload_lds16(const void* g, void* l) {
    __builtin_amdgcn_global_load_lds(
        (const __attribute__((address_space(1))) void*)g,
        (__attribute__((address_space(3))) void*)l, 16, 0, 0);
}

// ---------------------------------------------------------------------------
// Kernel A (byte-identical to r15/r17/r18): PRE-ARRANGED bf16 weights.
//  WdT_sw: [q][ck][(ks2*4+kg)*64 + j][m], value Wd[k][j],
//          k = q*256 + ck*64 + ks2*32 + kg*8 + m.
//  WuT_sw: r9's XOR swizzle pre-applied per 64KB col-half.
// ---------------------------------------------------------------------------
__global__ __launch_bounds__(256) void tt_build_w_kernel(
    const float* __restrict__ d1, const float* __restrict__ d2, const float* __restrict__ d3,
    const float* __restrict__ u1, const float* __restrict__ u2, const float* __restrict__ u3,
    unsigned short* __restrict__ WdT_sw, unsigned short* __restrict__ WuT_sw)
{
    int t = blockIdx.x * 256 + threadIdx.x;
    if (t < 65536) {
        int j = t >> 10, i = t & 1023;
        int i1 = i >> 7, i2 = (i >> 3) & 15, i3 = i & 7;
        int j1 = j >> 4, j2 = (j >> 2) & 3, j3 = j & 3;
        float t3[8];
#pragma unroll
        for (int b = 0; b < 8; ++b) t3[b] = d3[(b * 8 + i3) * 4 + j3];
        float wsum = 0.f;
#pragma unroll
        for (int a = 0; a < 8; ++a) {
            float va = d1[(i1 * 4 + j1) * 8 + a];
            const float* p2 = d2 + ((a * 16 + i2) * 4 + j2) * 8;
            float wa = 0.f;
#pragma unroll
            for (int b = 0; b < 8; ++b) wa = fmaf(p2[b], t3[b], wa);
            wsum = fmaf(va, wa, wsum);
        }
        int q_ = i >> 8, ck = (i >> 6) & 3, ks2 = (i >> 5) & 1;
        int kg_ = (i >> 3) & 3, m = i & 7;
        int off = (q_ * 4 + ck) * 4096 + ((ks2 * 4 + kg_) * 64 + j) * 8 + m;
        WdT_sw[off] = f2bf(wsum);
    } else {
        int t2 = t - 65536;
        int d = t2 >> 6, k = t2 & 63;
        int k1 = k >> 4, k2 = (k >> 2) & 3, k3 = k & 3;
        int o1 = d >> 7, o2 = (d >> 3) & 15, o3 = d & 7;
        float t3[8];
#pragma unroll
        for (int b = 0; b < 8; ++b) t3[b] = u3[(b * 4 + k3) * 8 + o3];
        float wsum = 0.f;
#pragma unroll
        for (int a = 0; a < 8; ++a) {
            float va = u1[(k1 * 8 + o1) * 8 + a];
            const float* p2 = u2 + ((a * 4 + k2) * 16 + o2) * 8;
            float wa = 0.f;
#pragma unroll
            for (int b = 0; b < 8; ++b) wa = fmaf(p2[b], t3[b], wa);
            wsum = fmaf(va, wa, wsum);
        }
        int dl = d & 511, hf = d >> 9;
        int off = hf * 32768 + (dl * 8 + ((k >> 3) ^ (dl & 7))) * 8 + (k & 7);
        WuT_sw[off] = f2bf(wsum);
    }
}

// ---------------------------------------------------------------------------
// FUSED kernel (r18 structure + hidden WuT staging). 256 blocks x 256 thr
// (4 waves), block = 4 row-tiles.
// Phase A (r17-verified): wave h = K-quarter; weights direct L2->VGPR; per
//   k-step {8 x + 4 W} pinned asm, dbuf 2-deep, counted vmcnt. NEW: ch0 WuT
//   staging (16 gload_lds -> wstage) issued after the LAST k-step issue,
//   fenced; final CPT waits become vmcnt(28)/vmcnt(16) (16 staging ops may
//   remain in flight). Reduce's __syncthreads() drains them for free.
// Reduce -> zlds (r4 stride-80 layout, verified).
// Phase B (r15-verified loop): ch0 computes from the prefetched wstage while
//   ch1 stages into the freed red region; one barrier between; no trailing
//   barrier. Port traffic unchanged (192 MB); serial staging stalls removed.
// LDS: red 64 + wstage 64 + zlds 10 = 138 KB -> 1 block/CU (as before).
// ---------------------------------------------------------------------------
__global__ __launch_bounds__(256) void tt_fused_kernel(
    const float* __restrict__ x, const unsigned short* __restrict__ WdT_sw,
    const unsigned short* __restrict__ WuT_sw, const float* __restrict__ bd,
    const float* __restrict__ bu, float* __restrict__ y)
{
    __shared__ float red[4][4][1024];            // 64 KB; reused as ch1 WuT
    __shared__ unsigned short wstage[32768];     // 64 KB; ch0 WuT (prefetched)
    __shared__ unsigned short zlds[4][16 * 80];  // 10 KB, r4-verified layout
    const int t = threadIdx.x;
    const int lane = t & 63;
    const int h = t >> 6;          // wave id: K-quarter (A) / col-128 (B)
    const int l15 = lane & 15;
    const int kg = lane >> 4;
    const int tile0 = blockIdx.x * 4;

    // reduce-phase constants (r9-verified mapping)
    const int colz = (t >> 6) * 16 + (t & 15);
    const int rowz = ((t & 63) >> 4) * 4;
    const float bdv = bd[colz];

    const float* xp0 = x + ((size_t)(tile0 + 0) * 16 + l15) * 1024 + h * 256 + kg * 8;
    const float* xp1 = xp0 + 16 * 1024;
    const float* xp2 = xp0 + 32 * 1024;
    const float* xp3 = xp0 + 48 * 1024;
    const unsigned short* wqb = WdT_sw + h * 16384 + kg * 512 + l15 * 8;
    const unsigned short* wq0 = wqb;
    const unsigned short* wq1 = wqb + 2048;
    const unsigned short* wq2 = wqb + 4096;
    const unsigned short* wq3 = wqb + 6144;
    const unsigned short* wq4 = wqb + 8192;
    const unsigned short* wq5 = wqb + 10240;
    const unsigned short* wq6 = wqb + 12288;
    const unsigned short* wq7 = wqb + 14336;

    f32x4 xA[8], xB[8];
    short8 wA[4], wB[4];
    f32x4 acc[4][4];
#pragma unroll
    for (int t4 = 0; t4 < 4; ++t4)
#pragma unroll
        for (int ct = 0; ct < 4; ++ct) acc[t4][ct] = {0.f, 0.f, 0.f, 0.f};

#define ISSUE(D, W, WQ, O0, O1)                                                                   \
    asm volatile("global_load_dwordx4 %0, %1, off offset:" #O0 : "=v"(D[0]) : "v"(xp0) : "memory"); \
    asm volatile("global_load_dwordx4 %0, %1, off offset:" #O1 : "=v"(D[1]) : "v"(xp0) : "memory"); \
    asm volatile("global_load_dwordx4 %0, %1, off offset:" #O0 : "=v"(D[2]) : "v"(xp1) : "memory"); \
    asm volatile("global_load_dwordx4 %0, %1, off offset:" #O1 : "=v"(D[3]) : "v"(xp1) : "memory"); \
    asm volatile("global_load_dwordx4 %0, %1, off offset:" #O0 : "=v"(D[4]) : "v"(xp2) : "memory"); \
    asm volatile("global_load_dwordx4 %0, %1, off offset:" #O1 : "=v"(D[5]) : "v"(xp2) : "memory"); \
    asm volatile("global_load_dwordx4 %0, %1, off offset:" #O0 : "=v"(D[6]) : "v"(xp3) : "memory"); \
    asm volatile("global_load_dwordx4 %0, %1, off offset:" #O1 : "=v"(D[7]) : "v"(xp3) : "memory"); \
    asm volatile("global_load_dwordx4 %0, %1, off offset:0"   : "=v"(W[0]) : "v"(WQ) : "memory");   \
    asm volatile("global_load_dwordx4 %0, %1, off offset:256" : "=v"(W[1]) : "v"(WQ) : "memory");   \
    asm volatile("global_load_dwordx4 %0, %1, off offset:512" : "=v"(W[2]) : "v"(WQ) : "memory");   \
    asm volatile("global_load_dwordx4 %0, %1, off offset:768" : "=v"(W[3]) : "v"(WQ) : "memory");

#define CPT(D, W, WN) do {                                                                   \
    asm volatile("s_waitcnt vmcnt(" #WN ")" ::: "memory");                                   \
    __builtin_amdgcn_sched_barrier(0);                                                       \
    _Pragma("unroll")                                                                        \
    for (int t4 = 0; t4 < 4; ++t4) {                                                         \
        union { short8 v; unsigned short e[8]; } a;                                          \
        _Pragma("unroll")                                                                    \
        for (int e = 0; e < 4; ++e) {                                                        \
            a.e[e]     = f2bf(D[2 * t4][e]);                                                 \
            a.e[e + 4] = f2bf(D[2 * t4 + 1][e]);                                             \
        }                                                                                    \
        _Pragma("unroll")                                                                    \
        for (int ct = 0; ct < 4; ++ct)                                                       \
            acc[t4][ct] = __builtin_amdgcn_mfma_f32_16x16x32_bf16(a.v, W[ct], acc[t4][ct],   \
                                                                  0, 0, 0);                  \
    }                                                                                        \
    __builtin_amdgcn_sched_barrier(0);                                                       \
} while (0)

    ISSUE(xA, wA, wq0, 0, 16)
    ISSUE(xB, wB, wq1, 128, 144)
    CPT(xA, wA, 12); ISSUE(xA, wA, wq2, 256, 272)
    CPT(xB, wB, 12); ISSUE(xB, wB, wq3, 384, 400)
    CPT(xA, wA, 12); ISSUE(xA, wA, wq4, 512, 528)
    CPT(xB, wB, 12); ISSUE(xB, wB, wq5, 640, 656)
    CPT(xA, wA, 12); ISSUE(xA, wA, wq6, 768, 784)
    CPT(xB, wB, 12); ISSUE(xB, wB, wq7, 896, 912)
    // ---- prefetch ch0 WuT into wstage (16 builtin gload_lds, fenced) -----
    // FIFO after this point: xA(wq6) 12 oldest, xB(wq7) 12, staging 16 newest.
    __builtin_amdgcn_sched_barrier(0);
    {
        const unsigned short* src0 = WuT_sw + h * 8192 + lane * 8;
#pragma unroll
        for (int i = 0; i < 16; ++i)
            gload_lds16(src0 + i * 512, wstage + h * 8192 + i * 512);
    }
    __builtin_amdgcn_sched_barrier(0);
    CPT(xA, wA, 28);      // xA drained (<=28 leaves xB+staging in flight)
    CPT(xB, wB, 16);      // xB drained (<=16 leaves staging in flight)
#undef ISSUE
#undef CPT

    // ---- reduce: acc -> red -> bias/relu -> zlds (r4-verified layout) -----
    // __syncthreads() also drains the tracked ch0 staging loads.
#pragma unroll
    for (int t4 = 0; t4 < 4; ++t4)
#pragma unroll
        for (int ct = 0; ct < 4; ++ct)
            *reinterpret_cast<f32x4*>(&red[t4][h][ct * 256 + lane * 4]) = acc[t4][ct];
    __syncthreads();
#pragma unroll
    for (int t4 = 0; t4 < 4; ++t4) {
        f32x4 v0 = *reinterpret_cast<const f32x4*>(&red[t4][0][t * 4]);
        f32x4 v1 = *reinterpret_cast<const f32x4*>(&red[t4][1][t * 4]);
        f32x4 v2 = *reinterpret_cast<const f32x4*>(&red[t4][2][t * 4]);
        f32x4 v3 = *reinterpret_cast<const f32x4*>(&red[t4][3][t * 4]);
#pragma unroll
        for (int r = 0; r < 4; ++r) {
            float zz = v0[r] + v1[r] + v2[r] + v3[r] + bdv;
            zz = zz > 0.f ? zz : 0.f;
            zlds[t4][(rowz + r) * 80 + colz] = f2bf(zz);
        }
    }
    __syncthreads();   // red free; zlds + wstage (ch0 WuT) visible

    // ---- phase B ----------------------------------------------------------
    unsigned short* wlds = reinterpret_cast<unsigned short*>(&red[0][0][0]);
    const int w = h;   // wave covers cols ch*512 + w*128 + [0,128)

    // issue ch1 staging into the freed red region (drained by next barrier)
    {
        const unsigned short* src1 = WuT_sw + 32768 + h * 8192 + lane * 8;
#pragma unroll
        for (int i = 0; i < 16; ++i)
            gload_lds16(src1 + i * 512, wlds + h * 8192 + i * 512);
    }

    // ---- ch0: compute from prefetched wstage ------------------------------
    {
        f32x4 bv[8];
#pragma unroll
        for (int i = 0; i < 8; ++i)
            bv[i] = *reinterpret_cast<const f32x4*>(bu + w * 128 + i * 16 + kg * 4);
#pragma unroll
        for (int tt = 0; tt < 4; ++tt) {
            const int tile = tile0 + tt;
            short8 az0 = *reinterpret_cast<const short8*>(&zlds[tt][l15 * 80 + kg * 8]);
            short8 az1 = *reinterpret_cast<const short8*>(&zlds[tt][l15 * 80 + 32 + kg * 8]);
            const size_t yb = (size_t)(tile * 16 + l15) * 1024 + w * 128;
#pragma unroll
            for (int i = 0; i < 8; ++i) {
                const int row = w * 128 + i * 16 + l15;
                const int s = row & 7;
                short8 b0 = *reinterpret_cast<const short8*>(&wstage[(row * 8 + (kg ^ s)) * 8]);
                short8 b1 = *reinterpret_cast<const short8*>(&wstage[(row * 8 + ((kg + 4) ^ s)) * 8]);
                f32x4 c = {0.f, 0.f, 0.f, 0.f};
                c = __builtin_amdgcn_mfma_f32_16x16x32_bf16(b0, az0, c, 0, 0, 0);
                c = __builtin_amdgcn_mfma_f32_16x16x32_bf16(b1, az1, c, 0, 0, 0);
                f32x4 o;
#pragma unroll
                for (int r = 0; r < 4; ++r) o[r] = c[r] + bv[i][r];
                *reinterpret_cast<f32x4*>(y + yb + i * 16 + kg * 4) = o;
            }
        }
    }
    __syncthreads();   // ch1 staging drained; wlds ready

    // ---- ch1: compute from wlds -------------------------------------------
    {
        f32x4 bv[8];
#pragma unroll
        for (int i = 0; i < 8; ++i)
            bv[i] = *reinterpret_cast<const f32x4*>(bu + 512 + w * 128 + i * 16 + kg * 4);
#pragma unroll
        for (int tt = 0; tt < 4; ++tt) {
            const int tile = tile0 + tt;
            short8 az0 = *reinterpret_cast<const short8*>(&zlds[tt][l15 * 80 + kg * 8]);
            short8 az1 = *reinterpret_cast<const short8*>(&zlds[tt][l15 * 80 + 32 + kg * 8]);
            const size_t yb = (size_t)(tile * 16 + l15) * 1024 + 512 + w * 128;
#pragma unroll
            for (int i = 0; i < 8; ++i) {
                const int row = w * 128 + i * 16 + l15;
                const int s = row & 7;
                short8 b0 = *reinterpret_cast<const short8*>(&wlds[(row * 8 + (kg ^ s)) * 8]);
                short8 b1 = *reinterpret_cast<const short8*>(&wlds[(row * 8 + ((kg + 4) ^ s)) * 8]);
                f32x4 c = {0.f, 0.f, 0.f, 0.f};
                c = __builtin_amdgcn_mfma_f32_16x16x32_bf16(b0, az0, c, 0, 0, 0);
                c = __builtin_amdgcn_mfma_f32_16x16x32_bf16(b1, az1, c, 0, 0, 0);
                f32x4 o;
#pragma unroll
                for (int r = 0; r < 4; ++r) o[r] = c[r] + bv[i][r];
                *reinterpret_cast<f32x4*>(y + yb + i * 16 + kg * 4) = o;
            }
        }
    }
}

extern "C" void kernel_launch(void* const* d_in, const int* in_sizes, int n_in,
                              void* d_out, int out_size, void* d_ws, size_t ws_size,
                              hipStream_t stream) {
    const float* x  = (const float*)d_in[0];
    const float* d1 = (const float*)d_in[1];
    const float* d2 = (const float*)d_in[2];
    const float* d3 = (const float*)d_in[3];
    const float* u1 = (const float*)d_in[4];
    const float* u2 = (const float*)d_in[5];
    const float* u3 = (const float*)d_in[6];
    const float* bd = (const float*)d_in[7];
    const float* bu = (const float*)d_in[8];
    float* y = (float*)d_out;
    unsigned short* WdT_sw = (unsigned short*)d_ws;   // 128 KB, staged layout
    unsigned short* WuT_sw = WdT_sw + 65536;          // 128 KB, pre-swizzled

    hipLaunchKernelGGL(tt_build_w_kernel, dim3(512), dim3(256), 0, stream,
                       d1, d2, d3, u1, u2, u3, WdT_sw, WuT_sw);
    hipLaunchKernelGGL(tt_fused_kernel, dim3(256), dim3(256), 0, stream,
                       x, WdT_sw, WuT_sw, bd, bu, y);
}